// Round 3
// baseline (3693.908 us; speedup 1.0000x reference)
//
#include <hip/hip_runtime.h>

typedef unsigned short u16;
typedef unsigned int   u32;

#define NTOK 294
#define KS_STRIDE 34   // u16 stride for Ks rows  (17 odd in dwords -> conflict-free over j)
#define VT_STRIDE 300  // u16 stride for Vt rows  (150 dwords -> 2-way max over c)
#define WST 260        // u16 stride for W/X f16 staging rows (130 dwords)
#define OBUF_BYTES 38535168ull   // 256*294*256 u16
#define FLAG_OFF (OBUF_BYTES)

typedef __fp16 hv2 __attribute__((ext_vector_type(2)));   // builtin-interop f16x2

__device__ __forceinline__ float b2f(u16 v){ union{u32 u; float f;} x; x.u = ((u32)v) << 16; return x.f; }
__device__ __forceinline__ u16 f2b(float f){
  union{float f; u32 u;} x; x.f = f; u32 u = x.u;
  return (u16)((u + 0x7fffu + ((u >> 16) & 1u)) >> 16);      // RTNE bf16
}
__device__ __forceinline__ u32 pack2h(float a, float b){
#if __has_builtin(__builtin_amdgcn_cvt_pkrtz)
  auto r = __builtin_amdgcn_cvt_pkrtz(a, b);
  union{ decltype(r) h; u32 u; } x; x.h = r; return x.u;
#else
  union{ hv2 h; u32 u; } x; x.h[0] = (__fp16)a; x.h[1] = (__fp16)b; return x.u;
#endif
}
// two bf16 packed in a dword -> two f16 packed in a dword (exact for our magnitudes)
__device__ __forceinline__ u32 bfp2h(u32 bfp){
  union{u32 u; float f;} lo, hi; lo.u = bfp << 16; hi.u = bfp & 0xffff0000u;
  return pack2h(lo.f, hi.f);
}
__device__ __forceinline__ u16 f2h(float a){ return (u16)(pack2h(a, 0.0f) & 0xffffu); }

__device__ __forceinline__ float dot2f(u32 a, u32 b, float c){
#if __has_builtin(__builtin_amdgcn_fdot2)
  union{u32 u; hv2 h;} A, B; A.u = a; B.u = b;
  return __builtin_amdgcn_fdot2(A.h, B.h, c, false);          // v_dot2_f32_f16
#else
  union{u32 u; __fp16 h[2];} A, B; A.u = a; B.u = b;
  return c + (float)A.h[0]*(float)B.h[0] + (float)A.h[1]*(float)B.h[1];
#endif
}

// -------------------------------------------------------------------------
// Probe: decide whether d_in[0] is bf16 (flag 0) or f32 (flag 1).
// bf16 N(0,1) data: exponent fields cluster near 127 -> ~0 outliers.
// f32 data misread as bf16: odd halves are mantissa bits -> ~38% outliers.
// -------------------------------------------------------------------------
__global__ void dfab_probe_kernel(const u16* __restrict__ X, int* __restrict__ flag)
{
  const int lane = threadIdx.x;   // 64 threads
  int cnt = 0;
#pragma unroll
  for (int k = 0; k < 8; ++k){
    u16 v = X[lane * 8 + k];
    int e = (v >> 7) & 0xFF;
    cnt += (e < 96 || e > 158) ? 1 : 0;
  }
  for (int off = 32; off > 0; off >>= 1) cnt += __shfl_xor(cnt, off);
  if (lane == 0) *flag = (cnt > 64) ? 1 : 0;
}

// -------------------------------------------------------------------------
// Kernel A: per (window, head): QKV (K,V into LDS) + biased/masked softmax
// attention; writes O[win][tok][h*32+c] (bf16) to workspace.
// grid 2048 (= 256 win * 8 heads), block 256 (4 waves). LDS = 59,736 B.
// -------------------------------------------------------------------------
__global__ __launch_bounds__(256) void dfab_attn_kernel(
    const void* __restrict__ Xv, const int* __restrict__ Mask,
    const void* __restrict__ Wqkvv, const void* __restrict__ BiasTv,
    const int* __restrict__ RelIdx, u16* __restrict__ Obuf,
    const int* __restrict__ flagp)
{
  __shared__ __align__(16) char lds[59736];
  u16* Ks   = (u16*)(lds);           // [294][34] f16
  u16* Vt   = (u16*)(lds + 19992);   // [32][300] f16 (transposed: [c][j])
  u16* Wp   = (u16*)(lds + 39192);   // phase1: [16][260] f16 weight piece
  u16* Xs   = (u16*)(lds + 47512);   // phase1: [16][260] f16 x tile
  u16* Wqt  = (u16*)(lds + 39192);   // phase2 union: [32][260] f16 Wq^T
  u32* Pb   = (u32*)(lds + 55832);   // [4][152] f16-pair p per wave
  float* Madd = (float*)(lds + 58264); // [304] 0 or -1e30
  u16* Qb   = (u16*)(lds + 59480);   // [4][32] f16 q row per wave

  const int tid = threadIdx.x;
  const int bx  = blockIdx.x;
  const int win = bx >> 3, h = bx & 7;

  const int f32m = *(const volatile int*)flagp;
  const u16*   Xb = (const u16*)Xv;       const float* Xf = (const float*)Xv;
  const u16*   Wb = (const u16*)Wqkvv;    const float* Wf = (const float*)Wqkvv;
  const u16*   Bb = (const u16*)BiasTv;   const float* Bf = (const float*)BiasTv;

  // ---- init: key mask (additive) + Vt tail zeros (PV reads j in [294,296)) ----
  for (int j = tid; j < 304; j += 256){
    float mv = -1e30f;
    if (j < NTOK){ int l = j / 49, r = j - l * 49;
      mv = (Mask[(win * 49 + r) * 6 + l] != 0) ? 0.0f : -1e30f; }
    Madd[j] = mv;
  }
  for (int idx = tid; idx < 32 * 6; idx += 256){
    int c = idx / 6; Vt[c * VT_STRIDE + NTOK + (idx - c * 6)] = 0;
  }

  // ---- phase 1: K and V (4 pieces of 16 cols), f16 dot2 GEMM ----
#pragma unroll 1
  for (int p = 0; p < 4; ++p){
    const int kind = p >> 1;                               // 0=K, 1=V
    const int colbase = 256 + kind * 256 + h * 32 + (p & 1) * 16;
    __syncthreads();
    for (int idx = tid; idx < 16 * 128; idx += 256){
      int c = idx & 15, d2 = idx >> 4;
      float w0, w1;
      if (f32m){ w0 = Wf[(2 * d2) * 768 + colbase + c]; w1 = Wf[(2 * d2 + 1) * 768 + colbase + c]; }
      else     { w0 = b2f(Wb[(2 * d2) * 768 + colbase + c]); w1 = b2f(Wb[(2 * d2 + 1) * 768 + colbase + c]); }
      *(u32*)&Wp[c * WST + 2 * d2] = pack2h(w0, w1);
    }
#pragma unroll 1
    for (int jt = 0; jt < 19; ++jt){
      const int j0 = jt * 16;
      const int nj = (NTOK - j0 < 16) ? (NTOK - j0) : 16;
      __syncthreads();
      for (int idx = tid; idx < nj * 128; idx += 256){
        int jl = idx >> 7, d2 = idx & 127;
        int tok = j0 + jl; int l = tok / 49, r = tok - l * 49;
        size_t off = (size_t)((l * 256 + win) * 49 + r) * 256 + 2 * d2;
        u32 hp;
        if (f32m){ float2 xx = *(const float2*)&Xf[off]; hp = pack2h(xx.x, xx.y); }
        else     { hp = bfp2h(*(const u32*)&Xb[off]); }
        *(u32*)&Xs[jl * WST + 2 * d2] = hp;
      }
      __syncthreads();
      const int jl = tid >> 4, c = tid & 15;
      const u32* xp = (const u32*)&Xs[jl * WST];
      const u32* wp = (const u32*)&Wp[c * WST];
      float a0 = 0.f, a1 = 0.f;
#pragma unroll 4
      for (int d2 = 0; d2 < 128; d2 += 4){
        uint2 xa = *(const uint2*)(xp + d2), xb = *(const uint2*)(xp + d2 + 2);
        uint2 wa = *(const uint2*)(wp + d2), wb = *(const uint2*)(wp + d2 + 2);
        a0 = dot2f(xa.x, wa.x, a0); a1 = dot2f(xa.y, wa.y, a1);
        a0 = dot2f(xb.x, wb.x, a0); a1 = dot2f(xb.y, wb.y, a1);
      }
      if (jl < nj){
        u16 hv = f2h(a0 + a1);
        int tok = j0 + jl;
        if (kind == 0) Ks[tok * KS_STRIDE + (p & 1) * 16 + c] = hv;
        else           Vt[((p & 1) * 16 + c) * VT_STRIDE + tok] = hv;
      }
    }
  }
  __syncthreads();
  // ---- stage Wq^T (overwrites Wp/Xs union) ----
  for (int idx = tid; idx < 32 * 128; idx += 256){
    int c = idx & 31, d2 = idx >> 5;
    float w0, w1;
    if (f32m){ w0 = Wf[(2 * d2) * 768 + h * 32 + c]; w1 = Wf[(2 * d2 + 1) * 768 + h * 32 + c]; }
    else     { w0 = b2f(Wb[(2 * d2) * 768 + h * 32 + c]); w1 = b2f(Wb[(2 * d2 + 1) * 768 + h * 32 + c]); }
    *(u32*)&Wqt[c * WST + 2 * d2] = pack2h(w0, w1);
  }
  __syncthreads();

  // ---- phase 2: per-wave query rows ----
  const int wave = tid >> 6, lane = tid & 63;
  const int hf = lane >> 5, c32 = lane & 31;
  u32* mypb = Pb + wave * 152;
  u16* qbw  = Qb + wave * 32;

  for (int i = wave; i < NTOK; i += 4){
    const int li = i / 49, ri = i - li * 49;
    const size_t rowoff = (size_t)((li * 256 + win) * 49 + ri) * 256;
    // q_c on the fly: lane (c32, hf) does half the d-range, combine via shfl
    const u32* wqp = (const u32*)&Wqt[c32 * WST];
    float q0 = 0.f, q1 = 0.f;
    if (f32m){
      const float4* xr4 = (const float4*)&Xf[rowoff];
#pragma unroll 4
      for (int d2 = hf * 64; d2 < hf * 64 + 64; d2 += 2){
        uint2 wq = *(const uint2*)(wqp + d2);
        float4 xx = xr4[d2 >> 1];
        q0 = dot2f(pack2h(xx.x, xx.y), wq.x, q0);
        q1 = dot2f(pack2h(xx.z, xx.w), wq.y, q1);
      }
    } else {
      const u32* xr = (const u32*)&Xb[rowoff];
#pragma unroll 4
      for (int d2 = hf * 64; d2 < hf * 64 + 64; d2 += 2){
        uint2 wq = *(const uint2*)(wqp + d2);
        q0 = dot2f(bfp2h(xr[d2]),     wq.x, q0);
        q1 = dot2f(bfp2h(xr[d2 + 1]), wq.y, q1);
      }
    }
    float qa = q0 + q1;
    qa += __shfl_xor(qa, 32);
    if (hf == 0) qbw[c32] = f2h(qa * 0.17677669529663687f);   // dh^-0.5
    __asm__ volatile("s_waitcnt lgkmcnt(0)" ::: "memory");
    u32 qp[16];
#pragma unroll
    for (int cc = 0; cc < 16; ++cc) qp[cc] = *(const u32*)&qbw[2 * cc];

    // scores: 5 strips of 64 keys
    float sv[5];
#pragma unroll
    for (int it = 0; it < 5; ++it){
      int j = it * 64 + lane;
      float a;
      if (j < NTOK){
        int nb = RelIdx[i * NTOK + j] * 8 + h;
        float bias = f32m ? Bf[nb] : b2f(Bb[nb]);
        float a0 = bias + Madd[j];
        float a1 = 0.f;
        const u16* kr = &Ks[j * KS_STRIDE];
#pragma unroll
        for (int cc = 0; cc < 16; cc += 2){
          a0 = dot2f(qp[cc],     *(const u32*)&kr[2 * cc],     a0);
          a1 = dot2f(qp[cc + 1], *(const u32*)&kr[2 * cc + 2], a1);
        }
        a = a0 + a1;
      } else a = -3e38f;
      sv[it] = a;
    }
    // softmax over 294 (distributed 5 per lane)
    float m = sv[0];
#pragma unroll
    for (int it = 1; it < 5; ++it) m = fmaxf(m, sv[it]);
    for (int off = 32; off > 0; off >>= 1) m = fmaxf(m, __shfl_xor(m, off));
    float lsum = 0.f;
#pragma unroll
    for (int it = 0; it < 5; ++it){ float e = __expf(sv[it] - m); sv[it] = e; lsum += e; }
    for (int off = 32; off > 0; off >>= 1) lsum += __shfl_xor(lsum, off);
    const float rinv = 1.0f / lsum;
    // pack normalized p as f16 pairs (even lane takes odd neighbor's value)
#pragma unroll
    for (int it = 0; it < 5; ++it){
      float pn = sv[it] * rinv;
      float po = __shfl_xor(pn, 1);
      int j = it * 64 + lane;
      if (!(lane & 1) && j < 304) mypb[j >> 1] = pack2h(pn, po);
    }
    __asm__ volatile("s_waitcnt lgkmcnt(0)" ::: "memory");
    // PV: lane (c32, hf) accumulates its half of the 294 (padded 296) keys
    const u16* vr = &Vt[c32 * VT_STRIDE];
    const int jb = hf * 148;
    float o0 = 0.f, o1 = 0.f;
#pragma unroll 4
    for (int g = 0; g < 37; ++g){
      int j = jb + 4 * g;
      uint2 vv = *(const uint2*)&vr[j];
      uint2 pp = *(const uint2*)&mypb[j >> 1];
      o0 = dot2f(pp.x, vv.x, o0);
      o1 = dot2f(pp.y, vv.y, o1);
    }
    float o = o0 + o1;
    o += __shfl_xor(o, 32);
    if (hf == 0)
      Obuf[(size_t)(win * NTOK + i) * 256 + h * 32 + c32] = f2b(o);
  }
}

// -------------------------------------------------------------------------
// Kernel B: out = O @ w_out, scattered to (l,x,y,w1,w2,d) layout.
// grid 2560 (= 256 win * 10 token-tiles of 32), block 256. LDS = 33,920 B.
// -------------------------------------------------------------------------
__global__ __launch_bounds__(256) void dfab_proj_kernel(
    const u16* __restrict__ Obuf, const void* __restrict__ Woutv,
    void* __restrict__ Outv, const int* __restrict__ flagp)
{
  __shared__ __align__(16) char lds[33920];
  u16* Ot = (u16*)(lds);           // [32][258] f16
  u16* Wt = (u16*)(lds + 16512);   // [256][34] f16 (transposed k-tile)

  const int tid = threadIdx.x;
  const int bx = blockIdx.x;
  const int win = bx / 10, tile = bx - win * 10;
  const int t0 = tile * 32;
  const int nt = (NTOK - t0 < 32) ? (NTOK - t0) : 32;

  const int f32m = *(const volatile int*)flagp;
  const u16* Wob = (const u16*)Woutv; const float* Wof = (const float*)Woutv;

  for (int idx = tid; idx < nt * 128; idx += 256){
    int t = idx >> 7, k2 = idx & 127;
    u32 oo = *(const u32*)&Obuf[(size_t)(win * NTOK + t0 + t) * 256 + 2 * k2];
    *(u32*)&Ot[t * 258 + 2 * k2] = bfp2h(oo);
  }

  float acc[32];
#pragma unroll
  for (int t = 0; t < 32; ++t) acc[t] = 0.f;
  const int dd = tid;

#pragma unroll 1
  for (int kt = 0; kt < 8; ++kt){
    __syncthreads();
    for (int idx = tid; idx < 4096; idx += 256){
      int d = idx & 255, kk2 = idx >> 8;        // kk2 in [0,16)
      int k = kt * 32 + 2 * kk2;
      float w0, w1;
      if (f32m){ w0 = Wof[k * 256 + d]; w1 = Wof[(k + 1) * 256 + d]; }
      else     { w0 = b2f(Wob[k * 256 + d]); w1 = b2f(Wob[(k + 1) * 256 + d]); }
      *(u32*)&Wt[d * 34 + 2 * kk2] = pack2h(w0, w1);
    }
    __syncthreads();
#pragma unroll 2
    for (int kk2 = 0; kk2 < 16; ++kk2){
      u32 wp = *(const u32*)&Wt[dd * 34 + 2 * kk2];
      const u16* orow = &Ot[kt * 32 + 2 * kk2];
#pragma unroll 8
      for (int t = 0; t < 32; ++t){
        u32 op = *(const u32*)&orow[t * 258];
        acc[t] = dot2f(op, wp, acc[t]);
      }
    }
  }

  for (int t = 0; t < nt; ++t){
    int tok = t0 + t; int l = tok / 49, r = tok - l * 49;
    size_t oidx = (size_t)((l * 256 + win) * 49 + r) * 256 + dd;
    if (f32m) ((float*)Outv)[oidx] = acc[t];
    else      ((u16*)Outv)[oidx]   = f2b(acc[t]);
  }
}

// -------------------------------------------------------------------------
extern "C" void kernel_launch(void* const* d_in, const int* in_sizes, int n_in,
                              void* d_out, int out_size, void* d_ws, size_t ws_size,
                              hipStream_t stream) {
  (void)in_sizes; (void)n_in; (void)out_size; (void)ws_size;
  const void* x          = d_in[0];             // bf16 OR f32 (1,6,16,16,7,7,256)
  const int*  mask       = (const int*)d_in[1]; // int32 (1,16,16,7,7,1,6)
  const void* w_qkv      = d_in[2];             // bf16 OR f32 (256,768)
  const void* w_out      = d_in[3];             // bf16 OR f32 (256,256)
  const void* bias_table = d_in[4];             // bf16 OR f32 (1859,8)
  const int*  rel_index  = (const int*)d_in[5]; // int32 (294,294)
  u16* obuf = (u16*)d_ws;                       // 38.5 MB bf16 O buffer
  int* flag = (int*)((char*)d_ws + FLAG_OFF);

  dfab_probe_kernel<<<1, 64, 0, stream>>>((const u16*)x, flag);
  dfab_attn_kernel<<<2048, 256, 0, stream>>>(x, mask, w_qkv, bias_table, rel_index, obuf, flag);
  dfab_proj_kernel<<<2560, 256, 0, stream>>>(obuf, w_out, d_out, flag);
}

// Round 4
// 842.206 us; speedup vs baseline: 4.3860x; 4.3860x over previous
//
#include <hip/hip_runtime.h>

typedef unsigned short u16;
typedef unsigned int   u32;

#define NTOK 294
#define KS_STRIDE 34
#define VT_STRIDE 300
#define WST 260
#define OBUF_BYTES 38535168ull   // old path: 256*294*256 u16
#define FLAG_OFF (OBUF_BYTES)    // old path flag location (proven to fit)

// ---- new-path workspace layout (bytes) ----
#define ROWS_ALLOC 75280ull                      // 75264 rows + 16 slack
#define BUFB (ROWS_ALLOC * 512ull)               // 38,543,360 per f16 [rows][256] buffer
#define QWS_OFF   0ull
#define KWS_OFF   (QWS_OFF + BUFB)
#define VWS_OFF   (KWS_OFF + BUFB)
#define OWS_OFF   (VWS_OFF + BUFB)
#define BIASM_OFF (OWS_OFF + BUFB)               // 8*304*304 f16 = 1,478,656
#define WQT_OFF   (BIASM_OFF + 1478656ull)       // 768*256 f16  = 393,216
#define WOT_OFF   (WQT_OFF + 393216ull)          // 256*256 f16  = 131,072
#define FLAG2_OFF (WOT_OFF + 131072ull)
#define NEED_WS   (FLAG2_OFF + 4ull)             // ~156.2 MB

typedef __fp16 hv2  __attribute__((ext_vector_type(2)));
typedef __fp16 f16x8 __attribute__((ext_vector_type(8)));
typedef float  f32x4 __attribute__((ext_vector_type(4)));

__device__ __forceinline__ float b2f(u16 v){ union{u32 u; float f;} x; x.u = ((u32)v) << 16; return x.f; }
__device__ __forceinline__ u16 f2b(float f){
  union{float f; u32 u;} x; x.f = f; u32 u = x.u;
  return (u16)((u + 0x7fffu + ((u >> 16) & 1u)) >> 16);      // RTNE bf16
}
__device__ __forceinline__ u32 pack2h(float a, float b){
#if __has_builtin(__builtin_amdgcn_cvt_pkrtz)
  auto r = __builtin_amdgcn_cvt_pkrtz(a, b);
  union{ decltype(r) h; u32 u; } x; x.h = r; return x.u;
#else
  union{ hv2 h; u32 u; } x; x.h[0] = (__fp16)a; x.h[1] = (__fp16)b; return x.u;
#endif
}
__device__ __forceinline__ u32 bfp2h(u32 bfp){
  union{u32 u; float f;} lo, hi; lo.u = bfp << 16; hi.u = bfp & 0xffff0000u;
  return pack2h(lo.f, hi.f);
}
__device__ __forceinline__ u16 f2h(float a){ return (u16)(pack2h(a, 0.0f) & 0xffffu); }

__device__ __forceinline__ float dot2f(u32 a, u32 b, float c){
#if __has_builtin(__builtin_amdgcn_fdot2)
  union{u32 u; hv2 h;} A, B; A.u = a; B.u = b;
  return __builtin_amdgcn_fdot2(A.h, B.h, c, false);
#else
  union{u32 u; __fp16 h[2];} A, B; A.u = a; B.u = b;
  return c + (float)A.h[0]*(float)B.h[0] + (float)A.h[1]*(float)B.h[1];
#endif
}

__device__ __forceinline__ f32x4 mfma16(f16x8 a, f16x8 b, f32x4 c){
  return __builtin_amdgcn_mfma_f32_16x16x32_f16(a, b, c, 0, 0, 0);
}

// -------------------------------------------------------------------------
// Probe: bf16 (flag 0) vs f32 (flag 1) input dtype, from exponent stats.
// -------------------------------------------------------------------------
__global__ void dfab_probe_kernel(const u16* __restrict__ X, int* __restrict__ flag)
{
  const int lane = threadIdx.x;   // 64 threads
  int cnt = 0;
#pragma unroll
  for (int k = 0; k < 8; ++k){
    u16 v = X[lane * 8 + k];
    int e = (v >> 7) & 0xFF;
    cnt += (e < 96 || e > 158) ? 1 : 0;
  }
  for (int off = 32; off > 0; off >>= 1) cnt += __shfl_xor(cnt, off);
  if (lane == 0) *flag = (cnt > 64) ? 1 : 0;
}

// =========================================================================
// NEW PATH
// =========================================================================

// prep: WqkvT[n][k] f16 (Q-scaled), WoutT[n][k] f16, BiasM[h][j][i] f16
__global__ __launch_bounds__(256) void dfab_prep_kernel(
    const void* __restrict__ Wqkvv, const void* __restrict__ Woutv,
    const void* __restrict__ BiasTv, const int* __restrict__ RelIdx,
    u16* __restrict__ wqt, u16* __restrict__ wot, u16* __restrict__ biasm,
    const int* __restrict__ flagp)
{
  const int f32m = *(const volatile int*)flagp;
  const u16* Wb = (const u16*)Wqkvv;  const float* Wf = (const float*)Wqkvv;
  const u16* Ob = (const u16*)Woutv;  const float* Of = (const float*)Woutv;
  const u16* Bb = (const u16*)BiasTv; const float* Bf = (const float*)BiasTv;
  int idx = blockIdx.x * 256 + threadIdx.x;          // grid 3912 -> 1,001,472
  if (idx < 196608){
    int n = idx >> 8, k = idx & 255;
    float w = f32m ? Wf[k*768 + n] : b2f(Wb[k*768 + n]);
    if (n < 256) w *= 0.17677669529663687f;          // fold dh^-0.5 into Wq
    wqt[n*256 + k] = f2h(w);
  } else if (idx < 262144){
    int t = idx - 196608; int n = t >> 8, k = t & 255;
    float w = f32m ? Of[k*256 + n] : b2f(Ob[k*256 + n]);
    wot[n*256 + k] = f2h(w);
  } else {
    int t = idx - 262144;
    int hh = t / 92416; int rem = t - hh * 92416;
    int j = rem / 304;  int i = rem - j * 304;
    float v = 0.f;
    if (i < NTOK && j < NTOK){
      int nb = RelIdx[i * NTOK + j] * 8 + hh;
      v = f32m ? Bf[nb] : b2f(Bb[nb]);
    }
    biasm[((size_t)(hh*304 + j))*304 + i] = f2h(v);
  }
}

// QKV GEMM: rows m = win*294+tok (M=75264), K=256, N=768 -> Q/K/V f16 ws
__global__ __launch_bounds__(256) void dfab_qkv_kernel(
    const void* __restrict__ Xv, const u16* __restrict__ wqt,
    u16* __restrict__ Qws, u16* __restrict__ Kws, u16* __restrict__ Vws,
    const int* __restrict__ flagp)
{
  __shared__ __align__(16) u16 Xs[64 * 264];         // 33,792 B
  const int tid = threadIdx.x;
  const int m0 = blockIdx.x * 64;
  const int f32m = *(const volatile int*)flagp;
  const u16* Xb = (const u16*)Xv; const float* Xf = (const float*)Xv;

  for (int idx = tid; idx < 64 * 128; idx += 256){
    int rl = idx >> 7, d2 = idx & 127;
    int m = m0 + rl; int win = m / 294, tok = m - win * 294;
    int l = tok / 49, r = tok - l * 49;
    size_t src = ((size_t)((l*256 + win)*49 + r))*256 + 2*d2;
    u32 hp = f32m ? pack2h(Xf[src], Xf[src+1]) : bfp2h(*(const u32*)&Xb[src]);
    *(u32*)&Xs[rl * 264 + 2*d2] = hp;
  }
  __syncthreads();

  const int wave = tid >> 6, lane = tid & 63;
  const int q = lane >> 4, n16 = lane & 15;
  f16x8 afr[8];
#pragma unroll
  for (int ks = 0; ks < 8; ++ks)
    afr[ks] = *(const f16x8*)&Xs[(wave*16 + n16) * 264 + ks*32 + q*8];

  u16* dsts[3] = { Qws, Kws, Vws };
#pragma unroll 1
  for (int nt = 0; nt < 48; ++nt){
    f16x8 bfr[8];
#pragma unroll
    for (int ks = 0; ks < 8; ++ks)
      bfr[ks] = *(const f16x8*)&wqt[(size_t)(nt*16 + n16) * 256 + ks*32 + q*8];
    f32x4 c = {0.f, 0.f, 0.f, 0.f};
#pragma unroll
    for (int ks = 0; ks < 8; ++ks) c = mfma16(afr[ks], bfr[ks], c);
    u16* dst = dsts[nt >> 4];
    int ncol = (nt & 15) * 16 + n16;
    size_t rowb = (size_t)(m0 + wave*16 + q*4);
#pragma unroll
    for (int r = 0; r < 4; ++r)
      dst[(rowb + r) * 256 + ncol] = f2h(c[r]);
  }
}

// Attention: block=(win,head); waves own independent 16-row m-tiles.
__global__ __launch_bounds__(256) void dfab_attn2_kernel(
    const u16* __restrict__ Qws, const u16* __restrict__ Kws,
    const u16* __restrict__ Vws, const u16* __restrict__ BiasM,
    const int* __restrict__ Mask, u16* __restrict__ Ows)
{
  __shared__ __align__(16) u16 Vt[32 * 328];         // 20,992 B (stride 328: 16B-aligned rows, 2-way banks)
  __shared__ __align__(16) u16 Pw[4][16 * 168];      // 21,504 B (stride 168: 16B-aligned rows)
  __shared__ float Madd[304];

  const int tid = threadIdx.x;
  const int win = blockIdx.x >> 3, h = blockIdx.x & 7;
  const int wave = tid >> 6, lane = tid & 63;
  const int q = lane >> 4, n16 = lane & 15;

  for (int j = tid; j < 304; j += 256){
    float mv = -1e30f;
    if (j < NTOK){ int l = j / 49, r = j - l * 49;
      mv = (Mask[(win * 49 + r) * 6 + l] != 0) ? 0.0f : -1e30f; }
    Madd[j] = mv;
  }
  // stage V transposed: Vt[c][tok]; zero tail toks
#pragma unroll 1
  for (int cc = 0; cc < 8; ++cc){
    int c = wave * 8 + cc;
#pragma unroll
    for (int tt = 0; tt < 5; ++tt){
      int tok = lane + 64 * tt;                      // 0..319
      u16 v = 0;
      if (tok < NTOK) v = Vws[((size_t)(win*NTOK + tok))*256 + h*32 + c];
      if (tok < 328) Vt[c * 328 + tok] = v;
    }
  }
  __syncthreads();

  u16* myP = Pw[wave];
#pragma unroll 1
  for (int mt = wave; mt < 19; mt += 4){
    const int m0 = mt * 16;
    f16x8 qf = *(const f16x8*)&Qws[((size_t)(win*NTOK + m0 + n16))*256 + h*32 + q*8];

    float S[19][4];
#pragma unroll
    for (int nt = 0; nt < 19; ++nt){
      const int j0 = nt * 16;
      f16x8 kf = *(const f16x8*)&Kws[((size_t)(win*NTOK + j0 + n16))*256 + h*32 + q*8];
      union { uint2 u; __fp16 hh[4]; } bu;
      bu.u = *(const uint2*)&BiasM[((size_t)(h*304 + j0 + n16))*304 + m0 + q*4];
      float madd = Madd[j0 + n16];
      f32x4 c = {0.f, 0.f, 0.f, 0.f};
      c = mfma16(qf, kf, c);
#pragma unroll
      for (int r = 0; r < 4; ++r) S[nt][r] = c[r] + (float)bu.hh[r] + madd;
    }
    // softmax per row (row = q*4+r lives in regs; cols across 16 lanes + 19 tiles)
    float rinv[4];
#pragma unroll
    for (int r = 0; r < 4; ++r){
      float mx = S[0][r];
#pragma unroll
      for (int nt = 1; nt < 19; ++nt) mx = fmaxf(mx, S[nt][r]);
      mx = fmaxf(mx, __shfl_xor(mx, 1));
      mx = fmaxf(mx, __shfl_xor(mx, 2));
      mx = fmaxf(mx, __shfl_xor(mx, 4));
      mx = fmaxf(mx, __shfl_xor(mx, 8));
      float sum = 0.f;
#pragma unroll
      for (int nt = 0; nt < 19; ++nt){ float e = __expf(S[nt][r] - mx); S[nt][r] = e; sum += e; }
      sum += __shfl_xor(sum, 1);
      sum += __shfl_xor(sum, 2);
      sum += __shfl_xor(sum, 4);
      sum += __shfl_xor(sum, 8);
      rinv[r] = 1.0f / sum;
    }
    // PV in two j-halves through LDS (C-layout -> A-layout)
    f32x4 o0 = {0.f,0.f,0.f,0.f}, o1 = {0.f,0.f,0.f,0.f};
#pragma unroll 1
    for (int half = 0; half < 2; ++half){
#pragma unroll
      for (int ntl = 0; ntl < 10; ++ntl){
        int nt = half * 10 + ntl;
        int col = ntl * 16 + n16;
#pragma unroll
        for (int r = 0; r < 4; ++r)
          myP[(q*4 + r) * 168 + col] = (nt < 19) ? f2h(S[nt][r]) : (u16)0;
      }
      __asm__ volatile("s_waitcnt lgkmcnt(0)" ::: "memory");
#pragma unroll
      for (int kk = 0; kk < 5; ++kk){
        f16x8 pf = *(const f16x8*)&myP[n16 * 168 + kk*32 + q*8];
        f16x8 v0 = *(const f16x8*)&Vt[n16 * 328 + half*160 + kk*32 + q*8];
        f16x8 v1 = *(const f16x8*)&Vt[(16 + n16) * 328 + half*160 + kk*32 + q*8];
        o0 = mfma16(pf, v0, o0);
        o1 = mfma16(pf, v1, o1);
      }
      __asm__ volatile("s_waitcnt lgkmcnt(0)" ::: "memory");
    }
#pragma unroll
    for (int r = 0; r < 4; ++r){
      int tok = m0 + q*4 + r;
      if (tok < NTOK){
        size_t base = ((size_t)(win*NTOK + tok))*256 + h*32;
        Ows[base + n16]      = f2h(o0[r] * rinv[r]);
        Ows[base + 16 + n16] = f2h(o1[r] * rinv[r]);
      }
    }
  }
}

// out-proj GEMM: Ows(75264x256) @ WoutT -> scatter to (l,x,y,w1,w2,d)
__global__ __launch_bounds__(256) void dfab_proj2_kernel(
    const u16* __restrict__ Ows, const u16* __restrict__ wot,
    void* __restrict__ Outv, const int* __restrict__ flagp)
{
  const int tid = threadIdx.x;
  const int wave = tid >> 6, lane = tid & 63;
  const int q = lane >> 4, n16 = lane & 15;
  const int mr = blockIdx.x * 64 + wave * 16;
  const int f32m = *(const volatile int*)flagp;

  f16x8 afr[8];
#pragma unroll
  for (int ks = 0; ks < 8; ++ks)
    afr[ks] = *(const f16x8*)&Ows[((size_t)(mr + n16))*256 + ks*32 + q*8];

  size_t obase[4];
#pragma unroll
  for (int r = 0; r < 4; ++r){
    int m = mr + q*4 + r; int win = m / 294, tok = m - win*294;
    int l = tok / 49, rr = tok - l*49;
    obase[r] = ((size_t)((l*256 + win)*49 + rr))*256;
  }

#pragma unroll 1
  for (int nt = 0; nt < 16; ++nt){
    f16x8 bfr[8];
#pragma unroll
    for (int ks = 0; ks < 8; ++ks)
      bfr[ks] = *(const f16x8*)&wot[(size_t)(nt*16 + n16) * 256 + ks*32 + q*8];
    f32x4 c = {0.f, 0.f, 0.f, 0.f};
#pragma unroll
    for (int ks = 0; ks < 8; ++ks) c = mfma16(afr[ks], bfr[ks], c);
    int ncol = nt*16 + n16;
    if (f32m){
#pragma unroll
      for (int r = 0; r < 4; ++r) ((float*)Outv)[obase[r] + ncol] = c[r];
    } else {
#pragma unroll
      for (int r = 0; r < 4; ++r) ((u16*)Outv)[obase[r] + ncol] = f2b(c[r]);
    }
  }
}

// =========================================================================
// OLD PATH (proven-correct fallback if workspace is too small)
// =========================================================================
__global__ __launch_bounds__(256) void dfab_attn_kernel(
    const void* __restrict__ Xv, const int* __restrict__ Mask,
    const void* __restrict__ Wqkvv, const void* __restrict__ BiasTv,
    const int* __restrict__ RelIdx, u16* __restrict__ Obuf,
    const int* __restrict__ flagp)
{
  __shared__ __align__(16) char lds[59736];
  u16* Ks   = (u16*)(lds);
  u16* Vt   = (u16*)(lds + 19992);
  u16* Wp   = (u16*)(lds + 39192);
  u16* Xs   = (u16*)(lds + 47512);
  u16* Wqt  = (u16*)(lds + 39192);
  u32* Pb   = (u32*)(lds + 55832);
  float* Madd = (float*)(lds + 58264);
  u16* Qb   = (u16*)(lds + 59480);

  const int tid = threadIdx.x;
  const int bx  = blockIdx.x;
  const int win = bx >> 3, h = bx & 7;

  const int f32m = *(const volatile int*)flagp;
  const u16*   Xb = (const u16*)Xv;       const float* Xf = (const float*)Xv;
  const u16*   Wb = (const u16*)Wqkvv;    const float* Wf = (const float*)Wqkvv;
  const u16*   Bb = (const u16*)BiasTv;   const float* Bf = (const float*)BiasTv;

  for (int j = tid; j < 304; j += 256){
    float mv = -1e30f;
    if (j < NTOK){ int l = j / 49, r = j - l * 49;
      mv = (Mask[(win * 49 + r) * 6 + l] != 0) ? 0.0f : -1e30f; }
    Madd[j] = mv;
  }
  for (int idx = tid; idx < 32 * 6; idx += 256){
    int c = idx / 6; Vt[c * VT_STRIDE + NTOK + (idx - c * 6)] = 0;
  }

#pragma unroll 1
  for (int p = 0; p < 4; ++p){
    const int kind = p >> 1;
    const int colbase = 256 + kind * 256 + h * 32 + (p & 1) * 16;
    __syncthreads();
    for (int idx = tid; idx < 16 * 128; idx += 256){
      int c = idx & 15, d2 = idx >> 4;
      float w0, w1;
      if (f32m){ w0 = Wf[(2 * d2) * 768 + colbase + c]; w1 = Wf[(2 * d2 + 1) * 768 + colbase + c]; }
      else     { w0 = b2f(Wb[(2 * d2) * 768 + colbase + c]); w1 = b2f(Wb[(2 * d2 + 1) * 768 + colbase + c]); }
      *(u32*)&Wp[c * WST + 2 * d2] = pack2h(w0, w1);
    }
#pragma unroll 1
    for (int jt = 0; jt < 19; ++jt){
      const int j0 = jt * 16;
      const int nj = (NTOK - j0 < 16) ? (NTOK - j0) : 16;
      __syncthreads();
      for (int idx = tid; idx < nj * 128; idx += 256){
        int jl = idx >> 7, d2 = idx & 127;
        int tok = j0 + jl; int l = tok / 49, r = tok - l * 49;
        size_t off = (size_t)((l * 256 + win) * 49 + r) * 256 + 2 * d2;
        u32 hp;
        if (f32m){ float2 xx = *(const float2*)&Xf[off]; hp = pack2h(xx.x, xx.y); }
        else     { hp = bfp2h(*(const u32*)&Xb[off]); }
        *(u32*)&Xs[jl * WST + 2 * d2] = hp;
      }
      __syncthreads();
      const int jl = tid >> 4, c = tid & 15;
      const u32* xp = (const u32*)&Xs[jl * WST];
      const u32* wp = (const u32*)&Wp[c * WST];
      float a0 = 0.f, a1 = 0.f;
#pragma unroll 4
      for (int d2 = 0; d2 < 128; d2 += 4){
        uint2 xa = *(const uint2*)(xp + d2), xb = *(const uint2*)(xp + d2 + 2);
        uint2 wa = *(const uint2*)(wp + d2), wb = *(const uint2*)(wp + d2 + 2);
        a0 = dot2f(xa.x, wa.x, a0); a1 = dot2f(xa.y, wa.y, a1);
        a0 = dot2f(xb.x, wb.x, a0); a1 = dot2f(xb.y, wb.y, a1);
      }
      if (jl < nj){
        u16 hv = f2h(a0 + a1);
        int tok = j0 + jl;
        if (kind == 0) Ks[tok * KS_STRIDE + (p & 1) * 16 + c] = hv;
        else           Vt[((p & 1) * 16 + c) * VT_STRIDE + tok] = hv;
      }
    }
  }
  __syncthreads();
  for (int idx = tid; idx < 32 * 128; idx += 256){
    int c = idx & 31, d2 = idx >> 5;
    float w0, w1;
    if (f32m){ w0 = Wf[(2 * d2) * 768 + h * 32 + c]; w1 = Wf[(2 * d2 + 1) * 768 + h * 32 + c]; }
    else     { w0 = b2f(Wb[(2 * d2) * 768 + h * 32 + c]); w1 = b2f(Wb[(2 * d2 + 1) * 768 + h * 32 + c]); }
    *(u32*)&Wqt[c * WST + 2 * d2] = pack2h(w0, w1);
  }
  __syncthreads();

  const int wave = tid >> 6, lane = tid & 63;
  const int hf = lane >> 5, c32 = lane & 31;
  u32* mypb = Pb + wave * 152;
  u16* qbw  = Qb + wave * 32;

  for (int i = wave; i < NTOK; i += 4){
    const int li = i / 49, ri = i - li * 49;
    const size_t rowoff = (size_t)((li * 256 + win) * 49 + ri) * 256;
    const u32* wqp = (const u32*)&Wqt[c32 * WST];
    float q0 = 0.f, q1 = 0.f;
    if (f32m){
      const float4* xr4 = (const float4*)&Xf[rowoff];
#pragma unroll 4
      for (int d2 = hf * 64; d2 < hf * 64 + 64; d2 += 2){
        uint2 wq = *(const uint2*)(wqp + d2);
        float4 xx = xr4[d2 >> 1];
        q0 = dot2f(pack2h(xx.x, xx.y), wq.x, q0);
        q1 = dot2f(pack2h(xx.z, xx.w), wq.y, q1);
      }
    } else {
      const u32* xr = (const u32*)&Xb[rowoff];
#pragma unroll 4
      for (int d2 = hf * 64; d2 < hf * 64 + 64; d2 += 2){
        uint2 wq = *(const uint2*)(wqp + d2);
        q0 = dot2f(bfp2h(xr[d2]),     wq.x, q0);
        q1 = dot2f(bfp2h(xr[d2 + 1]), wq.y, q1);
      }
    }
    float qa = q0 + q1;
    qa += __shfl_xor(qa, 32);
    if (hf == 0) qbw[c32] = f2h(qa * 0.17677669529663687f);
    __asm__ volatile("s_waitcnt lgkmcnt(0)" ::: "memory");
    u32 qp[16];
#pragma unroll
    for (int cc = 0; cc < 16; ++cc) qp[cc] = *(const u32*)&qbw[2 * cc];

    float sv[5];
#pragma unroll
    for (int it = 0; it < 5; ++it){
      int j = it * 64 + lane;
      float a;
      if (j < NTOK){
        int nb = RelIdx[i * NTOK + j] * 8 + h;
        float bias = f32m ? Bf[nb] : b2f(Bb[nb]);
        float a0 = bias + Madd[j];
        float a1 = 0.f;
        const u16* kr = &Ks[j * KS_STRIDE];
#pragma unroll
        for (int cc = 0; cc < 16; cc += 2){
          a0 = dot2f(qp[cc],     *(const u32*)&kr[2 * cc],     a0);
          a1 = dot2f(qp[cc + 1], *(const u32*)&kr[2 * cc + 2], a1);
        }
        a = a0 + a1;
      } else a = -3e38f;
      sv[it] = a;
    }
    float m = sv[0];
#pragma unroll
    for (int it = 1; it < 5; ++it) m = fmaxf(m, sv[it]);
    for (int off = 32; off > 0; off >>= 1) m = fmaxf(m, __shfl_xor(m, off));
    float lsum = 0.f;
#pragma unroll
    for (int it = 0; it < 5; ++it){ float e = __expf(sv[it] - m); sv[it] = e; lsum += e; }
    for (int off = 32; off > 0; off >>= 1) lsum += __shfl_xor(lsum, off);
    const float rinv = 1.0f / lsum;
#pragma unroll
    for (int it = 0; it < 5; ++it){
      float pn = sv[it] * rinv;
      float po = __shfl_xor(pn, 1);
      int j = it * 64 + lane;
      if (!(lane & 1) && j < 304) mypb[j >> 1] = pack2h(pn, po);
    }
    __asm__ volatile("s_waitcnt lgkmcnt(0)" ::: "memory");
    const u16* vr = &Vt[c32 * VT_STRIDE];
    const int jb = hf * 148;
    float o0 = 0.f, o1 = 0.f;
#pragma unroll 4
    for (int g = 0; g < 37; ++g){
      int j = jb + 4 * g;
      uint2 vv = *(const uint2*)&vr[j];
      uint2 pp = *(const uint2*)&mypb[j >> 1];
      o0 = dot2f(pp.x, vv.x, o0);
      o1 = dot2f(pp.y, vv.y, o1);
    }
    float o = o0 + o1;
    o += __shfl_xor(o, 32);
    if (hf == 0)
      Obuf[(size_t)(win * NTOK + i) * 256 + h * 32 + c32] = f2b(o);
  }
}

__global__ __launch_bounds__(256) void dfab_proj_kernel(
    const u16* __restrict__ Obuf, const void* __restrict__ Woutv,
    void* __restrict__ Outv, const int* __restrict__ flagp)
{
  __shared__ __align__(16) char lds[33920];
  u16* Ot = (u16*)(lds);
  u16* Wt = (u16*)(lds + 16512);

  const int tid = threadIdx.x;
  const int bx = blockIdx.x;
  const int win = bx / 10, tile = bx - win * 10;
  const int t0 = tile * 32;
  const int nt = (NTOK - t0 < 32) ? (NTOK - t0) : 32;

  const int f32m = *(const volatile int*)flagp;
  const u16* Wob = (const u16*)Woutv; const float* Wof = (const float*)Woutv;

  for (int idx = tid; idx < nt * 128; idx += 256){
    int t = idx >> 7, k2 = idx & 127;
    u32 oo = *(const u32*)&Obuf[(size_t)(win * NTOK + t0 + t) * 256 + 2 * k2];
    *(u32*)&Ot[t * 258 + 2 * k2] = bfp2h(oo);
  }

  float acc[32];
#pragma unroll
  for (int t = 0; t < 32; ++t) acc[t] = 0.f;
  const int dd = tid;

#pragma unroll 1
  for (int kt = 0; kt < 8; ++kt){
    __syncthreads();
    for (int idx = tid; idx < 4096; idx += 256){
      int d = idx & 255, kk2 = idx >> 8;
      int k = kt * 32 + 2 * kk2;
      float w0, w1;
      if (f32m){ w0 = Wof[k * 256 + d]; w1 = Wof[(k + 1) * 256 + d]; }
      else     { w0 = b2f(Wob[k * 256 + d]); w1 = b2f(Wob[(k + 1) * 256 + d]); }
      *(u32*)&Wt[d * 34 + 2 * kk2] = pack2h(w0, w1);
    }
    __syncthreads();
#pragma unroll 2
    for (int kk2 = 0; kk2 < 16; ++kk2){
      u32 wp = *(const u32*)&Wt[dd * 34 + 2 * kk2];
      const u16* orow = &Ot[kt * 32 + 2 * kk2];
#pragma unroll 8
      for (int t = 0; t < 32; ++t){
        u32 op = *(const u32*)&orow[t * 258];
        acc[t] = dot2f(op, wp, acc[t]);
      }
    }
  }

  for (int t = 0; t < nt; ++t){
    int tok = t0 + t; int l = tok / 49, r = tok - l * 49;
    size_t oidx = (size_t)((l * 256 + win) * 49 + r) * 256 + dd;
    if (f32m) ((float*)Outv)[oidx] = acc[t];
    else      ((u16*)Outv)[oidx]   = f2b(acc[t]);
  }
}

// -------------------------------------------------------------------------
extern "C" void kernel_launch(void* const* d_in, const int* in_sizes, int n_in,
                              void* d_out, int out_size, void* d_ws, size_t ws_size,
                              hipStream_t stream) {
  (void)in_sizes; (void)n_in; (void)out_size;
  const void* x          = d_in[0];
  const int*  mask       = (const int*)d_in[1];
  const void* w_qkv      = d_in[2];
  const void* w_out      = d_in[3];
  const void* bias_table = d_in[4];
  const int*  rel_index  = (const int*)d_in[5];
  char* ws = (char*)d_ws;

  if (ws_size >= NEED_WS){
    // MFMA path
    u16* qws   = (u16*)(ws + QWS_OFF);
    u16* kws   = (u16*)(ws + KWS_OFF);
    u16* vws   = (u16*)(ws + VWS_OFF);
    u16* ows   = (u16*)(ws + OWS_OFF);
    u16* biasm = (u16*)(ws + BIASM_OFF);
    u16* wqt   = (u16*)(ws + WQT_OFF);
    u16* wot   = (u16*)(ws + WOT_OFF);
    int* flag  = (int*)(ws + FLAG2_OFF);
    dfab_probe_kernel<<<1, 64, 0, stream>>>((const u16*)x, flag);
    dfab_prep_kernel<<<3912, 256, 0, stream>>>(w_qkv, w_out, bias_table, rel_index,
                                               wqt, wot, biasm, flag);
    dfab_qkv_kernel<<<1176, 256, 0, stream>>>(x, wqt, qws, kws, vws, flag);
    dfab_attn2_kernel<<<2048, 256, 0, stream>>>(qws, kws, vws, biasm, mask, ows);
    dfab_proj2_kernel<<<1176, 256, 0, stream>>>(ows, wot, d_out, flag);
  } else {
    // fallback: proven dot2 path
    u16* obuf = (u16*)ws;
    int* flag = (int*)(ws + FLAG_OFF);
    dfab_probe_kernel<<<1, 64, 0, stream>>>((const u16*)x, flag);
    dfab_attn_kernel<<<2048, 256, 0, stream>>>(x, mask, w_qkv, bias_table, rel_index, obuf, flag);
    dfab_proj_kernel<<<2560, 256, 0, stream>>>(obuf, w_out, d_out, flag);
  }
}